// Round 6
// baseline (270.190 us; speedup 1.0000x reference)
//
#include <hip/hip_runtime.h>
#include <math.h>

#define HH 1024
#define WW 2048
#define HW (HH*WW)
#define KC 32
#define CAP 65536
#define SENT 0xFFFFFFFFu
#define BIAS 16777216.0f  /* 2^24 */

typedef unsigned long long u64;

struct Scratch {              // hist first: aligned
  unsigned hist[2048];
  unsigned done0, done1, done2;
  int ncand, cnt, kRemain, nvalid;
  unsigned prefix;
  float scale;
  float ck[KC], m2cy[KC], m2cx[KC];
};

__device__ __forceinline__ unsigned agent_load(const unsigned* p){
  return __hip_atomic_load(p, __ATOMIC_RELAXED, __HIP_MEMORY_SCOPE_AGENT);
}
__device__ __forceinline__ void agent_store(unsigned* p, unsigned v){
  __hip_atomic_store(p, v, __ATOMIC_RELAXED, __HIP_MEMORY_SCOPE_AGENT);
}

// 256-thread parallel k-th-bucket selection over sc->hist (agent-coherent reads)
template<int PASS>
__device__ void do_pick(Scratch* sc, const float* rch, unsigned* wsum){
  int t = threadIdx.x;
  unsigned v[8];
  #pragma unroll
  for (int j=0;j<8;j++) v[j] = agent_load(&sc->hist[t*8+j]);
  unsigned s = 0;
  #pragma unroll
  for (int j=0;j<8;j++) s += v[j];
  unsigned incl = s;
  #pragma unroll
  for (int d=1; d<64; d<<=1){ unsigned o = __shfl_up(incl, d); if ((t&63) >= d) incl += o; }
  unsigned excl = incl - s;
  if ((t&63)==63) wsum[t>>6] = incl;
  __syncthreads();
  unsigned woff=0, total=0;
  #pragma unroll
  for (int w=0;w<4;w++){ unsigned xw=wsum[w]; if (w < (t>>6)) woff += xw; total += xw; }
  unsigned pre = woff + excl;
  int k;
  if (PASS==0){
    if (t==0) sc->cnt = (int)total;
    k = (total>0) ? (int)((total-1)>>1) : 0;
  } else {
    k = sc->kRemain;
  }
  if (total>0 && (unsigned)k >= pre && (unsigned)k < pre + s){
    unsigned kr = (unsigned)k - pre;
    int b_ = 0;
    #pragma unroll
    for (int j=0;j<8;j++){
      if (kr < v[j]){ b_ = t*8+j; break; }
      kr -= v[j];
    }
    sc->kRemain = (int)kr;
    if (PASS==0)      sc->prefix = (unsigned)b_;
    else if (PASS==1) sc->prefix = (sc->prefix << 11) | (unsigned)b_;
    else {
      unsigned key = (sc->prefix << 10) | (unsigned)b_;
      sc->scale = rch[0] / __uint_as_float(key);
    }
  }
  if (PASS==2 && t==0 && total==0) sc->scale = 0.0f;
  if (PASS < 2){
    __syncthreads();
    #pragma unroll
    for (int j=0;j<8;j++) agent_store(&sc->hist[t*8+j], 0u);
  }
}

__global__ __launch_bounds__(1024) void k_init(Scratch* sc){
  int t = threadIdx.x;
  ((uint2*)sc->hist)[t] = make_uint2(0u,0u);
  if (t==0){ sc->ncand=0; sc->done0=0u; sc->done1=0u; sc->done2=0u; }
}

// fused: heat-candidate collect + surface-normal heights + pass-0 hist (+ticket pick0)
// one row per block, 8 px per thread
__global__ __launch_bounds__(256) void kA(const float* __restrict__ heat,
    const int* __restrict__ sem, const float* __restrict__ depth,
    const float* __restrict__ invK, u64* __restrict__ cand,
    Scratch* __restrict__ sc, unsigned* __restrict__ hbuf){
  __shared__ unsigned hsh[2048];
  __shared__ unsigned wsum[4];
  __shared__ int lastf;
  int t = threadIdx.x;
  #pragma unroll
  for (int j=t;j<2048;j+=256) hsh[j]=0u;
  __syncthreads();

  int y = blockIdx.x;
  int row = y<<11;
  int x0 = t<<3;
  int p = row + x0;

  float4 h0 = ((const float4*)heat)[p>>2];
  float4 h1 = ((const float4*)heat)[(p>>2)+1];
  int4   s0 = ((const int4*)sem)[p>>2];
  int4   s1 = ((const int4*)sem)[(p>>2)+1];
  float4 c0 = ((const float4*)depth)[p>>2];
  float4 c1 = ((const float4*)depth)[(p>>2)+1];
  float  dl = depth[row + (x0>0 ? x0-1 : 0)];
  float  dr = depth[row + (x0+8<WW ? x0+8 : WW-1)];
  int rowu = (y>0)?    row-WW : row;
  int rowd = (y<HH-1)? row+WW : row;
  float4 u0q = ((const float4*)depth)[(rowu+x0)>>2];
  float4 u1q = ((const float4*)depth)[((rowu+x0)>>2)+1];
  float4 d0q = ((const float4*)depth)[(rowd+x0)>>2];
  float4 d1q = ((const float4*)depth)[((rowd+x0)>>2)+1];
  float ik0=invK[0],ik1=invK[1],ik2=invK[2];
  float ik3=invK[3],ik4=invK[4],ik5=invK[5];
  float ik6=invK[6],ik7=invK[7],ik8=invK[8];

  float hv[8] = {h0.x,h0.y,h0.z,h0.w,h1.x,h1.y,h1.z,h1.w};
  int   sv[8] = {s0.x,s0.y,s0.z,s0.w,s1.x,s1.y,s1.z,s1.w};
  float dcv[8]= {c0.x,c0.y,c0.z,c0.w,c1.x,c1.y,c1.z,c1.w};
  float duv[8]= {u0q.x,u0q.y,u0q.z,u0q.w,u1q.x,u1q.y,u1q.z,u1q.w};
  float ddv[8]= {d0q.x,d0q.y,d0q.z,d0q.w,d1q.x,d1q.y,d1q.z,d1q.w};

  // --- candidate collect: wave-aggregated compaction ---
  unsigned npos = 0;
  #pragma unroll
  for (int j=0;j<8;j++) npos += (hv[j] > 0.0f) ? 1u : 0u;
  unsigned incl = npos;
  #pragma unroll
  for (int d=1; d<64; d<<=1){ unsigned o = __shfl_up(incl, d); if ((t&63) >= d) incl += o; }
  unsigned wtot = __shfl(incl, 63);
  if (wtot){
    unsigned base = 0;
    if ((t&63)==63) base = (unsigned)atomicAdd(&sc->ncand, (int)wtot);
    base = __shfl(base, 63);
    unsigned slot = base + incl - npos;
    #pragma unroll
    for (int j=0;j<8;j++){
      if (hv[j] > 0.0f){
        if (slot < CAP)
          cand[slot] = ((u64)__float_as_uint(hv[j])<<32) | (u64)(unsigned)(~(unsigned)(p+j));
        slot++;
      }
    }
  }

  // --- surface-normal heights ---
  float fy = (float)y;
  float a0=ik1*fy+ik2, a1=ik4*fy+ik5, a2=ik7*fy+ik8;
  float fyu=(y>0)?    fy-1.0f : fy;
  float fyd=(y<HH-1)? fy+1.0f : fy;
  float uu0=ik1*fyu+ik2, uu1=ik4*fyu+ik5, uu2=ik7*fyu+ik8;
  float ww0=ik1*fyd+ik2, ww1=ik4*fyd+ik5, ww2=ik7*fyd+ik8;
  unsigned hk[8];
  #pragma unroll
  for (int j=0;j<8;j++){
    float fx  = (float)(x0+j);
    float dm  = (j==0)? dl : dcv[j-1];
    float dp  = (j==7)? dr : dcv[j+1];
    float fxm = (x0+j>0)?    fx-1.0f : fx;
    float fxp = (x0+j<WW-1)? fx+1.0f : fx;
    float pc0=(ik0*fx +a0)*dcv[j], pc1=(ik3*fx +a1)*dcv[j], pc2=(ik6*fx +a2)*dcv[j];
    float pm0=(ik0*fxm+a0)*dm,    pm1=(ik3*fxm+a1)*dm,    pm2=(ik6*fxm+a2)*dm;
    float pp0=(ik0*fxp+a0)*dp,    pp1=(ik3*fxp+a1)*dp,    pp2=(ik6*fxp+a2)*dp;
    float pu0=(ik0*fx+uu0)*duv[j], pu1=(ik3*fx+uu1)*duv[j], pu2=(ik6*fx+uu2)*duv[j];
    float pd0=(ik0*fx+ww0)*ddv[j], pd1=(ik3*fx+ww1)*ddv[j], pd2=(ik6*fx+ww2)*ddv[j];
    float vx0=pp0-pm0, vx1=pp1-pm1, vx2=pp2-pm2;
    float vy0=pd0-pu0, vy1=pd1-pu1, vy2=pd2-pu2;
    float n0=vx1*vy2-vx2*vy1, n1=vx2*vy0-vx0*vy2, n2=vx0*vy1-vx1*vy0;
    float nn = sqrtf(n0*n0+n1*n1+n2*n2) + 1e-8f;
    float h  = fabsf(pc0*n0+pc1*n1+pc2*n2) / nn;
    unsigned hb = __float_as_uint(h);
    bool g = (sv[j]==0);
    hk[j] = g ? hb : SENT;
    if (g) atomicAdd(&hsh[hb>>21], 1u);
  }
  ((uint4*)hbuf)[p>>2]     = make_uint4(hk[0],hk[1],hk[2],hk[3]);
  ((uint4*)hbuf)[(p>>2)+1] = make_uint4(hk[4],hk[5],hk[6],hk[7]);

  __syncthreads();
  for (int j=t;j<2048;j+=256){ unsigned v=hsh[j]; if (v) atomicAdd(&sc->hist[j], v); }
  __threadfence();
  __syncthreads();
  if (t==0) lastf = (atomicAdd(&sc->done0, 1u) == (unsigned)(gridDim.x-1)) ? 1 : 0;
  __syncthreads();
  if (lastf) do_pick<0>(sc, (const float*)0, wsum);
}

// 1024 threads = 16 waves: per-wave register top-32 + 16-way merge
__global__ __launch_bounds__(1024) void k_select(const u64* __restrict__ cand, Scratch* sc){
  __shared__ u64 loc[16*KC];
  int t = threadIdx.x;
  int lane = t & 63;
  int w = t >> 6;
  int n = sc->ncand; if (n > CAP) n = CAP;

  if (t < 16*KC) loc[t] = 0ULL;
  __syncthreads();

  int chunk = (n + 15) >> 4;
  int start = w * chunk;
  int end   = min(n, start + chunk);

  u64 rv[8];
  #pragma unroll
  for (int i=0;i<8;i++){
    int idx = start + lane + (i<<6);
    rv[i] = (idx < end) ? cand[idx] : 0ULL;
  }
  bool over = (end - start) > 512;

  u64 prev = ~0ULL;
  for (int r=0;r<KC;r++){
    u64 best = 0ULL;
    #pragma unroll
    for (int i=0;i<8;i++){ u64 key = rv[i]; if (key < prev && key > best) best = key; }
    if (over){
      for (int idx = start + 512 + lane; idx < end; idx += 64){
        u64 key = cand[idx]; if (key < prev && key > best) best = key;
      }
    }
    #pragma unroll
    for (int m=32;m>=1;m>>=1){ u64 o = __shfl_xor(best, m); if (o > best) best = o; }
    if (best == 0ULL) break;
    if (lane == 0) loc[w*KC + r] = best;
    prev = best;
  }
  __syncthreads();

  if (w == 0){
    int ptr = lane * KC;
    int lim = ptr + KC;
    int k = 0;
    for (int r=0;r<KC;r++){
      u64 key = (lane < 16 && ptr < lim) ? loc[ptr] : 0ULL;
      u64 mx = key;
      #pragma unroll
      for (int m=32;m>=1;m>>=1){ u64 o = __shfl_xor(mx, m); if (o > mx) mx = o; }
      if (mx == 0ULL) break;
      u64 ball = __ballot(key == mx);
      int winner = __ffsll((long long)ball) - 1;
      if (lane == winner) ptr++;
      if (lane == 0){
        unsigned idx = ~(unsigned)(mx & 0xFFFFFFFFULL);
        float cy = (float)(idx >> 11), cx = (float)(idx & 2047u);
        sc->ck[r]   = cy*cy + cx*cx + BIAS;
        sc->m2cy[r] = -2.0f*cy;
        sc->m2cx[r] = -2.0f*cx;
      }
      k = r + 1;
    }
    if (lane == 0) sc->nvalid = k;
  }
}

template<int PASS>
__global__ __launch_bounds__(256) void k_hist(const unsigned* __restrict__ hbuf,
    Scratch* __restrict__ sc, const float* __restrict__ rch){
  __shared__ unsigned hsh[2048];
  __shared__ unsigned wsum[4];
  __shared__ int lastf;
  int t = threadIdx.x;
  for (int j=t;j<2048;j+=256) hsh[j]=0u;
  __syncthreads();
  unsigned pref = sc->prefix;
  for (int i = blockIdx.x*256 + t; i < HW/4; i += gridDim.x*256){
    uint4 kv = ((const uint4*)hbuf)[i];
    unsigned ks[4] = {kv.x, kv.y, kv.z, kv.w};
    #pragma unroll
    for (int j=0;j<4;j++){
      unsigned key = ks[j];
      if (key == SENT) continue;
      if (PASS==1){ if ((key>>21) == pref) atomicAdd(&hsh[(key>>10)&2047u], 1u); }
      else        { if ((key>>10) == pref) atomicAdd(&hsh[key & 1023u], 1u); }
    }
  }
  __syncthreads();
  for (int j=t;j<2048;j+=256){ unsigned v=hsh[j]; if (v) atomicAdd(&sc->hist[j], v); }
  __threadfence();
  __syncthreads();
  if (t==0) lastf = (atomicAdd((PASS==1)? &sc->done1 : &sc->done2, 1u) == (unsigned)(gridDim.x-1)) ? 1 : 0;
  __syncthreads();
  if (lastf) do_pick<PASS>(sc, rch, wsum);
}

// labels + scaled depth + cam_out; one row per block, 8 px per thread (stride-256)
__global__ __launch_bounds__(256) void k_final(const int* __restrict__ sem,
    const float* __restrict__ off, const float* __restrict__ depth,
    const float* __restrict__ invK, const Scratch* __restrict__ sc,
    float* __restrict__ out){
  __shared__ float sck[KC], smy[KC], smx[KC];
  __shared__ int snv; __shared__ float ssc;
  int t = threadIdx.x;
  if (t < KC){ sck[t]=sc->ck[t]; smy[t]=sc->m2cy[t]; smx[t]=sc->m2cx[t]; }
  if (t == 0){ snv = sc->nvalid; ssc = sc->scale; }
  __syncthreads();

  int y = blockIdx.x;
  int row = y<<11;
  int sv[8]; float oyv[8], oxv[8], dv[8];
  #pragma unroll
  for (int j=0;j<8;j++){
    int px = row + (j<<8) + t;
    sv[j] = sem[px]; oyv[j] = off[px]; oxv[j] = off[HW+px]; dv[j] = depth[px];
  }
  float ik0=invK[0],ik1=invK[1],ik2=invK[2];
  float ik3=invK[3],ik4=invK[4],ik5=invK[5];
  float ik6=invK[6],ik7=invK[7],ik8=invK[8];
  float fy = (float)y;
  float a0=ik1*fy+ik2, a1=ik4*fy+ik5, a2=ik7*fy+ik8;
  int nv = snv; float s = ssc;

  float ys[8], xs[8]; unsigned ub[8];
  #pragma unroll
  for (int j=0;j<8;j++){
    int x = (j<<8)+t;
    ys[j] = fy + oyv[j]; xs[j] = (float)x + oxv[j]; ub[j] = SENT;
  }
  for (int k=0;k<nv;k++){
    float ckk=sck[k], my=smy[k], mx=smx[k];
    #pragma unroll
    for (int j=0;j<8;j++){
      float tt = fmaf(ys[j], my, ckk);
      tt = fmaf(xs[j], mx, tt);
      unsigned u = (__float_as_uint(tt) & ~31u) | (unsigned)k;
      ub[j] = u < ub[j] ? u : ub[j];
    }
  }
  float4* cam = (float4*)(out + (size_t)2*HW);
  #pragma unroll
  for (int j=0;j<8;j++){
    int x = (j<<8)+t; int px = row + x;
    int sj = sv[j];
    float lab = (sj >= 11 && nv > 0) ? (float)(sj*1000 + (int)(ub[j]&31u) + 1) : (float)sj;
    float fx = (float)x;
    float ds = dv[j]*s;
    float p0=(ik0*fx+a0)*ds, p1=(ik3*fx+a1)*ds, p2=(ik6*fx+a2)*ds;
    bool filt = (lab==10.0f) || (lab==19.0f);
    out[px] = lab;
    out[HW+px] = filt ? 0.0f : ds;
    cam[px] = make_float4(p0, p1, p2, lab);
  }
}

extern "C" void kernel_launch(void* const* d_in, const int* in_sizes, int n_in,
                              void* d_out, int out_size, void* d_ws, size_t ws_size,
                              hipStream_t stream){
  const int*   sem   = (const int*)d_in[0];
  const float* heat  = (const float*)d_in[1];
  const float* off   = (const float*)d_in[2];
  const float* depth = (const float*)d_in[3];
  const float* invK  = (const float*)d_in[4];
  const float* rch   = (const float*)d_in[5];
  float* out = (float*)d_out;

  unsigned* hbuf = (unsigned*)d_ws;                                      // HW*4 bytes
  u64* cand = (u64*)((char*)d_ws + (size_t)HW*4);                        // CAP*8 bytes
  Scratch* sc = (Scratch*)((char*)d_ws + (size_t)HW*4 + (size_t)CAP*8);

  k_init<<<1, 1024, 0, stream>>>(sc);
  kA<<<HH, 256, 0, stream>>>(heat, sem, depth, invK, cand, sc, hbuf);
  k_select<<<1, 1024, 0, stream>>>(cand, sc);
  k_hist<1><<<512, 256, 0, stream>>>(hbuf, sc, rch);
  k_hist<2><<<512, 256, 0, stream>>>(hbuf, sc, rch);
  k_final<<<HH, 256, 0, stream>>>(sem, off, depth, invK, sc, out);
}

// Round 7
// 128.688 us; speedup vs baseline: 2.0996x; 2.0996x over previous
//
#include <hip/hip_runtime.h>
#include <math.h>

#define HH 1024
#define WW 2048
#define HW (HH*WW)
#define KC 32
#define CAP 65536
#define SENT 0xFFFFFFFFu
#define BIAS 16777216.0f  /* 2^24 */

typedef unsigned long long u64;

struct Scratch {              // hist first: aligned
  unsigned hist[2048];
  unsigned done0, done1, done2;
  int ncand, cnt, kRemain, nvalid;
  unsigned prefix;
  float scale;
  float ck[KC], m2cy[KC], m2cx[KC];
};

__device__ __forceinline__ unsigned agent_load(const unsigned* p){
  return __hip_atomic_load(p, __ATOMIC_RELAXED, __HIP_MEMORY_SCOPE_AGENT);
}
__device__ __forceinline__ void agent_store(unsigned* p, unsigned v){
  __hip_atomic_store(p, v, __ATOMIC_RELAXED, __HIP_MEMORY_SCOPE_AGENT);
}

// 256-thread parallel k-th-bucket selection over sc->hist (agent-coherent reads)
template<int PASS>
__device__ void do_pick(Scratch* sc, const float* rch, unsigned* wsum){
  int t = threadIdx.x;
  unsigned v[8];
  #pragma unroll
  for (int j=0;j<8;j++) v[j] = agent_load(&sc->hist[t*8+j]);
  unsigned s = 0;
  #pragma unroll
  for (int j=0;j<8;j++) s += v[j];
  unsigned incl = s;
  #pragma unroll
  for (int d=1; d<64; d<<=1){ unsigned o = __shfl_up(incl, d); if ((t&63) >= d) incl += o; }
  unsigned excl = incl - s;
  if ((t&63)==63) wsum[t>>6] = incl;
  __syncthreads();
  unsigned woff=0, total=0;
  #pragma unroll
  for (int w=0;w<4;w++){ unsigned xw=wsum[w]; if (w < (t>>6)) woff += xw; total += xw; }
  unsigned pre = woff + excl;
  int k;
  if (PASS==0){
    if (t==0) sc->cnt = (int)total;
    k = (total>0) ? (int)((total-1)>>1) : 0;
  } else {
    k = sc->kRemain;
  }
  if (total>0 && (unsigned)k >= pre && (unsigned)k < pre + s){
    unsigned kr = (unsigned)k - pre;
    int b_ = 0;
    #pragma unroll
    for (int j=0;j<8;j++){
      if (kr < v[j]){ b_ = t*8+j; break; }
      kr -= v[j];
    }
    sc->kRemain = (int)kr;
    if (PASS==0)      sc->prefix = (unsigned)b_;
    else if (PASS==1) sc->prefix = (sc->prefix << 11) | (unsigned)b_;
    else {
      unsigned key = (sc->prefix << 10) | (unsigned)b_;
      sc->scale = rch[0] / __uint_as_float(key);
    }
  }
  if (PASS==2 && t==0 && total==0) sc->scale = 0.0f;
  if (PASS < 2){
    __syncthreads();
    #pragma unroll
    for (int j=0;j<8;j++) agent_store(&sc->hist[t*8+j], 0u);
  }
}

__global__ __launch_bounds__(1024) void k_init(Scratch* sc){
  int t = threadIdx.x;
  ((uint2*)sc->hist)[t] = make_uint2(0u,0u);
  if (t==0){ sc->ncand=0; sc->done0=0u; sc->done1=0u; sc->done2=0u; }
}

// fused: heat-candidate collect + surface-normal heights + pass-0 hist (+ticket pick0)
// one row per block, 8 px per thread
__global__ __launch_bounds__(256) void kA(const float* __restrict__ heat,
    const int* __restrict__ sem, const float* __restrict__ depth,
    const float* __restrict__ invK, u64* __restrict__ cand,
    Scratch* __restrict__ sc, unsigned* __restrict__ hbuf){
  __shared__ unsigned hsh[2048];
  __shared__ unsigned wsum[4];
  __shared__ int lastf;
  int t = threadIdx.x;
  #pragma unroll
  for (int j=t;j<2048;j+=256) hsh[j]=0u;
  __syncthreads();

  int y = blockIdx.x;
  int row = y<<11;
  int x0 = t<<3;
  int p = row + x0;

  float4 h0 = ((const float4*)heat)[p>>2];
  float4 h1 = ((const float4*)heat)[(p>>2)+1];
  int4   s0 = ((const int4*)sem)[p>>2];
  int4   s1 = ((const int4*)sem)[(p>>2)+1];
  float4 c0 = ((const float4*)depth)[p>>2];
  float4 c1 = ((const float4*)depth)[(p>>2)+1];
  float  dl = depth[row + (x0>0 ? x0-1 : 0)];
  float  dr = depth[row + (x0+8<WW ? x0+8 : WW-1)];
  int rowu = (y>0)?    row-WW : row;
  int rowd = (y<HH-1)? row+WW : row;
  float4 u0q = ((const float4*)depth)[(rowu+x0)>>2];
  float4 u1q = ((const float4*)depth)[((rowu+x0)>>2)+1];
  float4 d0q = ((const float4*)depth)[(rowd+x0)>>2];
  float4 d1q = ((const float4*)depth)[((rowd+x0)>>2)+1];
  float ik0=invK[0],ik1=invK[1],ik2=invK[2];
  float ik3=invK[3],ik4=invK[4],ik5=invK[5];
  float ik6=invK[6],ik7=invK[7],ik8=invK[8];

  float hv[8] = {h0.x,h0.y,h0.z,h0.w,h1.x,h1.y,h1.z,h1.w};
  int   sv[8] = {s0.x,s0.y,s0.z,s0.w,s1.x,s1.y,s1.z,s1.w};
  float dcv[8]= {c0.x,c0.y,c0.z,c0.w,c1.x,c1.y,c1.z,c1.w};
  float duv[8]= {u0q.x,u0q.y,u0q.z,u0q.w,u1q.x,u1q.y,u1q.z,u1q.w};
  float ddv[8]= {d0q.x,d0q.y,d0q.z,d0q.w,d1q.x,d1q.y,d1q.z,d1q.w};

  // --- candidate collect: wave-aggregated compaction ---
  unsigned npos = 0;
  #pragma unroll
  for (int j=0;j<8;j++) npos += (hv[j] > 0.0f) ? 1u : 0u;
  unsigned incl = npos;
  #pragma unroll
  for (int d=1; d<64; d<<=1){ unsigned o = __shfl_up(incl, d); if ((t&63) >= d) incl += o; }
  unsigned wtot = __shfl(incl, 63);
  if (wtot){
    unsigned base = 0;
    if ((t&63)==63) base = (unsigned)atomicAdd(&sc->ncand, (int)wtot);
    base = __shfl(base, 63);
    unsigned slot = base + incl - npos;
    #pragma unroll
    for (int j=0;j<8;j++){
      if (hv[j] > 0.0f){
        if (slot < CAP)
          cand[slot] = ((u64)__float_as_uint(hv[j])<<32) | (u64)(unsigned)(~(unsigned)(p+j));
        slot++;
      }
    }
  }

  // --- surface-normal heights ---
  float fy = (float)y;
  float a0=ik1*fy+ik2, a1=ik4*fy+ik5, a2=ik7*fy+ik8;
  float fyu=(y>0)?    fy-1.0f : fy;
  float fyd=(y<HH-1)? fy+1.0f : fy;
  float uu0=ik1*fyu+ik2, uu1=ik4*fyu+ik5, uu2=ik7*fyu+ik8;
  float ww0=ik1*fyd+ik2, ww1=ik4*fyd+ik5, ww2=ik7*fyd+ik8;
  unsigned hk[8];
  #pragma unroll
  for (int j=0;j<8;j++){
    float fx  = (float)(x0+j);
    float dm  = (j==0)? dl : dcv[j-1];
    float dp  = (j==7)? dr : dcv[j+1];
    float fxm = (x0+j>0)?    fx-1.0f : fx;
    float fxp = (x0+j<WW-1)? fx+1.0f : fx;
    float pc0=(ik0*fx +a0)*dcv[j], pc1=(ik3*fx +a1)*dcv[j], pc2=(ik6*fx +a2)*dcv[j];
    float pm0=(ik0*fxm+a0)*dm,    pm1=(ik3*fxm+a1)*dm,    pm2=(ik6*fxm+a2)*dm;
    float pp0=(ik0*fxp+a0)*dp,    pp1=(ik3*fxp+a1)*dp,    pp2=(ik6*fxp+a2)*dp;
    float pu0=(ik0*fx+uu0)*duv[j], pu1=(ik3*fx+uu1)*duv[j], pu2=(ik6*fx+uu2)*duv[j];
    float pd0=(ik0*fx+ww0)*ddv[j], pd1=(ik3*fx+ww1)*ddv[j], pd2=(ik6*fx+ww2)*ddv[j];
    float vx0=pp0-pm0, vx1=pp1-pm1, vx2=pp2-pm2;
    float vy0=pd0-pu0, vy1=pd1-pu1, vy2=pd2-pu2;
    float n0=vx1*vy2-vx2*vy1, n1=vx2*vy0-vx0*vy2, n2=vx0*vy1-vx1*vy0;
    float nn = sqrtf(n0*n0+n1*n1+n2*n2) + 1e-8f;
    float h  = fabsf(pc0*n0+pc1*n1+pc2*n2) / nn;
    unsigned hb = __float_as_uint(h);
    bool g = (sv[j]==0);
    hk[j] = g ? hb : SENT;
    if (g) atomicAdd(&hsh[hb>>21], 1u);
  }
  ((uint4*)hbuf)[p>>2]     = make_uint4(hk[0],hk[1],hk[2],hk[3]);
  ((uint4*)hbuf)[(p>>2)+1] = make_uint4(hk[4],hk[5],hk[6],hk[7]);

  __syncthreads();
  for (int j=t;j<2048;j+=256){ unsigned v=hsh[j]; if (v) atomicAdd(&sc->hist[j], v); }
  __syncthreads();   // drains vmcnt: this block's hist atomics complete before ticket
  if (t==0) lastf = (atomicAdd(&sc->done0, 1u) == (unsigned)(gridDim.x-1)) ? 1 : 0;
  __syncthreads();
  if (lastf) do_pick<0>(sc, (const float*)0, wsum);
}

// 1024 threads = 16 waves: per-wave register top-32 + 16-way merge
__global__ __launch_bounds__(1024) void k_select(const u64* __restrict__ cand, Scratch* sc){
  __shared__ u64 loc[16*KC];
  int t = threadIdx.x;
  int lane = t & 63;
  int w = t >> 6;
  int n = sc->ncand; if (n > CAP) n = CAP;

  if (t < 16*KC) loc[t] = 0ULL;
  __syncthreads();

  int chunk = (n + 15) >> 4;
  int start = w * chunk;
  int end   = min(n, start + chunk);

  u64 rv[8];
  #pragma unroll
  for (int i=0;i<8;i++){
    int idx = start + lane + (i<<6);
    rv[i] = (idx < end) ? cand[idx] : 0ULL;
  }
  bool over = (end - start) > 512;

  u64 prev = ~0ULL;
  for (int r=0;r<KC;r++){
    u64 best = 0ULL;
    #pragma unroll
    for (int i=0;i<8;i++){ u64 key = rv[i]; if (key < prev && key > best) best = key; }
    if (over){
      for (int idx = start + 512 + lane; idx < end; idx += 64){
        u64 key = cand[idx]; if (key < prev && key > best) best = key;
      }
    }
    #pragma unroll
    for (int m=32;m>=1;m>>=1){ u64 o = __shfl_xor(best, m); if (o > best) best = o; }
    if (best == 0ULL) break;
    if (lane == 0) loc[w*KC + r] = best;
    prev = best;
  }
  __syncthreads();

  if (w == 0){
    int ptr = lane * KC;
    int lim = ptr + KC;
    int k = 0;
    for (int r=0;r<KC;r++){
      u64 key = (lane < 16 && ptr < lim) ? loc[ptr] : 0ULL;
      u64 mx = key;
      #pragma unroll
      for (int m=32;m>=1;m>>=1){ u64 o = __shfl_xor(mx, m); if (o > mx) mx = o; }
      if (mx == 0ULL) break;
      u64 ball = __ballot(key == mx);
      int winner = __ffsll((long long)ball) - 1;
      if (lane == winner) ptr++;
      if (lane == 0){
        unsigned idx = ~(unsigned)(mx & 0xFFFFFFFFULL);
        float cy = (float)(idx >> 11), cx = (float)(idx & 2047u);
        sc->ck[r]   = cy*cy + cx*cx + BIAS;
        sc->m2cy[r] = -2.0f*cy;
        sc->m2cx[r] = -2.0f*cx;
      }
      k = r + 1;
    }
    if (lane == 0) sc->nvalid = k;
  }
}

template<int PASS>
__global__ __launch_bounds__(256) void k_hist(const unsigned* __restrict__ hbuf,
    Scratch* __restrict__ sc, const float* __restrict__ rch){
  __shared__ unsigned hsh[2048];
  __shared__ unsigned wsum[4];
  __shared__ int lastf;
  int t = threadIdx.x;
  for (int j=t;j<2048;j+=256) hsh[j]=0u;
  __syncthreads();
  unsigned pref = sc->prefix;
  for (int i = blockIdx.x*256 + t; i < HW/4; i += gridDim.x*256){
    uint4 kv = ((const uint4*)hbuf)[i];
    unsigned ks[4] = {kv.x, kv.y, kv.z, kv.w};
    #pragma unroll
    for (int j=0;j<4;j++){
      unsigned key = ks[j];
      if (key == SENT) continue;
      if (PASS==1){ if ((key>>21) == pref) atomicAdd(&hsh[(key>>10)&2047u], 1u); }
      else        { if ((key>>10) == pref) atomicAdd(&hsh[key & 1023u], 1u); }
    }
  }
  __syncthreads();
  for (int j=t;j<2048;j+=256){ unsigned v=hsh[j]; if (v) atomicAdd(&sc->hist[j], v); }
  __syncthreads();   // drains vmcnt before ticket
  if (t==0) lastf = (atomicAdd((PASS==1)? &sc->done1 : &sc->done2, 1u) == (unsigned)(gridDim.x-1)) ? 1 : 0;
  __syncthreads();
  if (lastf) do_pick<PASS>(sc, rch, wsum);
}

// labels + scaled depth + cam_out; one row per block, 8 px per thread (stride-256)
__global__ __launch_bounds__(256) void k_final(const int* __restrict__ sem,
    const float* __restrict__ off, const float* __restrict__ depth,
    const float* __restrict__ invK, const Scratch* __restrict__ sc,
    float* __restrict__ out){
  __shared__ float sck[KC], smy[KC], smx[KC];
  __shared__ int snv; __shared__ float ssc;
  int t = threadIdx.x;
  if (t < KC){ sck[t]=sc->ck[t]; smy[t]=sc->m2cy[t]; smx[t]=sc->m2cx[t]; }
  if (t == 0){ snv = sc->nvalid; ssc = sc->scale; }
  __syncthreads();

  int y = blockIdx.x;
  int row = y<<11;
  int sv[8]; float oyv[8], oxv[8], dv[8];
  #pragma unroll
  for (int j=0;j<8;j++){
    int px = row + (j<<8) + t;
    sv[j] = sem[px]; oyv[j] = off[px]; oxv[j] = off[HW+px]; dv[j] = depth[px];
  }
  float ik0=invK[0],ik1=invK[1],ik2=invK[2];
  float ik3=invK[3],ik4=invK[4],ik5=invK[5];
  float ik6=invK[6],ik7=invK[7],ik8=invK[8];
  float fy = (float)y;
  float a0=ik1*fy+ik2, a1=ik4*fy+ik5, a2=ik7*fy+ik8;
  int nv = snv; float s = ssc;

  float ys[8], xs[8]; unsigned ub[8];
  #pragma unroll
  for (int j=0;j<8;j++){
    int x = (j<<8)+t;
    ys[j] = fy + oyv[j]; xs[j] = (float)x + oxv[j]; ub[j] = SENT;
  }
  for (int k=0;k<nv;k++){
    float ckk=sck[k], my=smy[k], mx=smx[k];
    #pragma unroll
    for (int j=0;j<8;j++){
      float tt = fmaf(ys[j], my, ckk);
      tt = fmaf(xs[j], mx, tt);
      unsigned u = (__float_as_uint(tt) & ~31u) | (unsigned)k;
      ub[j] = u < ub[j] ? u : ub[j];
    }
  }
  float4* cam = (float4*)(out + (size_t)2*HW);
  #pragma unroll
  for (int j=0;j<8;j++){
    int x = (j<<8)+t; int px = row + x;
    int sj = sv[j];
    float lab = (sj >= 11 && nv > 0) ? (float)(sj*1000 + (int)(ub[j]&31u) + 1) : (float)sj;
    float fx = (float)x;
    float ds = dv[j]*s;
    float p0=(ik0*fx+a0)*ds, p1=(ik3*fx+a1)*ds, p2=(ik6*fx+a2)*ds;
    bool filt = (lab==10.0f) || (lab==19.0f);
    out[px] = lab;
    out[HW+px] = filt ? 0.0f : ds;
    cam[px] = make_float4(p0, p1, p2, lab);
  }
}

extern "C" void kernel_launch(void* const* d_in, const int* in_sizes, int n_in,
                              void* d_out, int out_size, void* d_ws, size_t ws_size,
                              hipStream_t stream){
  const int*   sem   = (const int*)d_in[0];
  const float* heat  = (const float*)d_in[1];
  const float* off   = (const float*)d_in[2];
  const float* depth = (const float*)d_in[3];
  const float* invK  = (const float*)d_in[4];
  const float* rch   = (const float*)d_in[5];
  float* out = (float*)d_out;

  unsigned* hbuf = (unsigned*)d_ws;                                      // HW*4 bytes
  u64* cand = (u64*)((char*)d_ws + (size_t)HW*4);                        // CAP*8 bytes
  Scratch* sc = (Scratch*)((char*)d_ws + (size_t)HW*4 + (size_t)CAP*8);

  k_init<<<1, 1024, 0, stream>>>(sc);
  kA<<<HH, 256, 0, stream>>>(heat, sem, depth, invK, cand, sc, hbuf);
  k_select<<<1, 1024, 0, stream>>>(cand, sc);
  k_hist<1><<<512, 256, 0, stream>>>(hbuf, sc, rch);
  k_hist<2><<<512, 256, 0, stream>>>(hbuf, sc, rch);
  k_final<<<HH, 256, 0, stream>>>(sem, off, depth, invK, sc, out);
}